// Round 11
// baseline (114.201 us; speedup 1.0000x reference)
//
#include <hip/hip_runtime.h>
#include <math.h>

#define N_SPK 1024
#define M_UTT 32
#define M_ENR 16
#define M_TEST 16
#define D 512
#define N_TEST_ROWS (N_SPK * M_TEST)   // 16384
#define NBLK_GEMM 512

// gemm: block = 512 thr (8 waves), tile 64spk x 512test, wave = 64 x 64
// (acc[4][4] = 64 AGPR, ni=4 keeps the LDS af-read floor at minimum).
// As = 64 KB -> 2 blocks/CU; launch_bounds(512,4) -> <=128 unified regs
// -> 4 waves/SIMD. NO software pipeline: single B buffer, load-then-use;
// TLP (4 waves/SIMD) hides the L2/L3 latency (m114 overlap model).
// Reg budget: 64 acc + 16 b + 8 af + 8 bp + ~20 misc ~= 116 < 128 (no spill;
// R5's ring pushed this to ~132 and spilled).
// Fused finalize via atomic counter (R8-proven pattern).

typedef __attribute__((ext_vector_type(4))) float f32x4;
typedef __attribute__((ext_vector_type(8))) short short8;
typedef __attribute__((ext_vector_type(8))) unsigned short ushort8;

typedef const __attribute__((address_space(1))) void g_void;
typedef __attribute__((address_space(3))) void lds_void;

__device__ __forceinline__ unsigned short f2bf(float f) {
    unsigned int u = __float_as_uint(f);
    u += 0x7FFF + ((u >> 16) & 1);   // round-to-nearest-even
    return (unsigned short)(u >> 16);
}

// ---------------------------------------------------------------------------
// Kernel 1: centroids + test-row normalize; blocks [0,4) zero g_row/g_pos/cnt.
// (R3-verbatim compute paths)
// ---------------------------------------------------------------------------
__global__ __launch_bounds__(256) void prep_kernel(const float* __restrict__ emb,
                                                   unsigned short* __restrict__ cent,
                                                   unsigned short* __restrict__ test,
                                                   float* __restrict__ g_row,
                                                   float* __restrict__ g_pos,
                                                   unsigned int* __restrict__ cnt) {
    const int b = blockIdx.x;
    const int tid = threadIdx.x;
    const int lane = tid & 63;
    const int wid = tid >> 6;

    if (b < 4) {
        g_row[b * 256 + tid] = 0.f;
        g_pos[b * 256 + tid] = 0.f;
        if (b == 0 && tid == 0) *cnt = 0u;
    }

    if (b < N_SPK) {
        const float* base = emb + (size_t)b * M_UTT * D;
        float a0 = 0.f, a1 = 0.f;
#pragma unroll
        for (int u = 0; u < M_ENR; ++u) {
            a0 += base[u * D + tid];
            a1 += base[u * D + tid + 256];
        }
        a0 *= (1.f / 16.f);
        a1 *= (1.f / 16.f);
        float ss = a0 * a0 + a1 * a1;
#pragma unroll
        for (int m = 1; m < 64; m <<= 1) ss += __shfl_xor(ss, m, 64);
        __shared__ float wss[4];
        if (lane == 0) wss[wid] = ss;
        __syncthreads();
        const float tot = wss[0] + wss[1] + wss[2] + wss[3];
        const float inv = 1.f / fmaxf(sqrtf(tot), 1e-8f);
        cent[b * D + tid] = f2bf(a0 * inv);
        cent[b * D + tid + 256] = f2bf(a1 * inv);
    } else {
        const int r = (b - N_SPK) * 4 + wid;   // test row 0..16383
        const int s = r >> 4, t = r & 15;
        const float* row = emb + ((size_t)s * M_UTT + M_ENR + t) * D;
        const f32x4* rv = (const f32x4*)row;
        const f32x4 v0 = rv[lane * 2];
        const f32x4 v1 = rv[lane * 2 + 1];
        float ss = v0[0]*v0[0] + v0[1]*v0[1] + v0[2]*v0[2] + v0[3]*v0[3]
                 + v1[0]*v1[0] + v1[1]*v1[1] + v1[2]*v1[2] + v1[3]*v1[3];
#pragma unroll
        for (int m = 1; m < 64; m <<= 1) ss += __shfl_xor(ss, m, 64);
        const float inv = 1.f / fmaxf(sqrtf(ss), 1e-8f);
        ushort8 o;
        o[0] = f2bf(v0[0] * inv); o[1] = f2bf(v0[1] * inv);
        o[2] = f2bf(v0[2] * inv); o[3] = f2bf(v0[3] * inv);
        o[4] = f2bf(v1[0] * inv); o[5] = f2bf(v1[1] * inv);
        o[6] = f2bf(v1[2] * inv); o[7] = f2bf(v1[3] * inv);
        *(ushort8*)&test[(size_t)r * D + lane * 8] = o;
    }
}

// ---------------------------------------------------------------------------
// Kernel 2: 2-block/CU, 4-wave/SIMD GEMM (TLP-hidden loads) + fused finalize.
// ---------------------------------------------------------------------------
__global__ __launch_bounds__(512, 4) void gemm_kernel(const unsigned short* __restrict__ A,  // cent 1024x512
                                                      const unsigned short* __restrict__ B,  // test 16384x512
                                                      const float* __restrict__ alpha_p,
                                                      const float* __restrict__ beta_p,
                                                      float* __restrict__ g_row,
                                                      float* __restrict__ g_pos,
                                                      unsigned int* __restrict__ cnt,
                                                      float* __restrict__ out) {
    __shared__ __align__(16) unsigned short As[64 * 512];   // 64 KB, swizzled
    __shared__ float rowsum[64];
    __shared__ float possum[64];
    __shared__ unsigned int last_flag;
    __shared__ float ws2[8];

    const int tid = threadIdx.x;
    const int lane = tid & 63;
    const int w = tid >> 6;          // wave 0..7, owns test cols [w*64, +64)
    const int l15 = lane & 15;

    // XCD swizzle: 512 blocks = 8 XCDs x 64.
    const int raw = blockIdx.x;
    const int wg = (raw & 7) * 64 + (raw >> 3);
    const int bi = wg & 15;          // 16 speaker panels (64 rows)
    const int bj = wg >> 4;          // 32 test panels (512 cols)
    const int row0 = bi * 64, col0 = bj * 512;
    const bool has_diag = ((bj >> 1) == bi);

    // ---- stage cent panel once: LDS[r][e] = A[row0+r][ e ^ ((r&7)<<3) ]
#pragma unroll
    for (int it = 0; it < 8; ++it) {
        const int r = it * 8 + w;    // r&7 == w&7 (wave-uniform swizzle const)
        const int src = (row0 + r) * D + ((lane * 8) ^ ((r & 7) << 3));
        __builtin_amdgcn_global_load_lds((g_void*)&A[src],
                                         (lds_void*)&As[r * D], 16, 0, 0);
    }
    if (tid < 64) { rowsum[tid] = 0.f; possum[tid] = 0.f; }

    const int bcol = col0 + w * 64;
    const unsigned short* bp[4];
#pragma unroll
    for (int ni = 0; ni < 4; ++ni)
        bp[ni] = &B[(size_t)(bcol + ni * 16 + l15) * D + (lane >> 4) * 8];

    // swizzled LDS read offset: (kk + (lane>>4)*8) ^ ((lane&7)<<3) = kk ^ hs
    const int hs = ((lane >> 4) * 8) ^ ((lane & 7) << 3);
    const int arow_base = l15 * D;

    f32x4 acc[4][4] = {};

    __syncthreads();   // A staged (drains vmcnt before barrier)

#pragma unroll
    for (int ko = 0; ko < D; ko += 32) {
        short8 b[4];
#pragma unroll
        for (int ni = 0; ni < 4; ++ni)
            b[ni] = *(const short8*)(bp[ni] + ko);        // k folds into imm
        const int ofs = ko ^ hs;
#pragma unroll
        for (int mi = 0; mi < 4; ++mi) {
            const short8 af = *(const short8*)&As[mi * 16 * D + arow_base + ofs];
#pragma unroll
            for (int ni = 0; ni < 4; ++ni)
                acc[mi][ni] = __builtin_amdgcn_mfma_f32_16x16x32_bf16(
                    af, b[ni], acc[mi][ni], 0, 0, 0);
        }
    }

    // ---- epilogue: e = exp(alpha*s + beta); row totals + diagonal sums.
    // C/D layout (16x16x32): col = lane&15, row = (lane>>4)*4 + reg   [m89]
    const float alpha = *alpha_p;
    const float beta = *beta_p;
#pragma unroll
    for (int mi = 0; mi < 4; ++mi) {
#pragma unroll
        for (int r = 0; r < 4; ++r) {
            const int lrow = mi * 16 + ((lane >> 4) << 2) + r;
            const int grow = row0 + lrow;
            float tot = 0.f, pos = 0.f;
#pragma unroll
            for (int ni = 0; ni < 4; ++ni) {
                const int gcol = bcol + ni * 16 + l15;
                const float e = __expf(fmaf(alpha, acc[mi][ni][r], beta));
                tot += e;
                if (has_diag) pos += ((gcol >> 4) == grow) ? e : 0.f;
            }
#pragma unroll
            for (int m = 1; m < 16; m <<= 1) tot += __shfl_xor(tot, m, 64);
            if (has_diag) {
#pragma unroll
                for (int m = 1; m < 16; m <<= 1) pos += __shfl_xor(pos, m, 64);
            }
            if (l15 == 0) {
                atomicAdd(&rowsum[lrow], tot);
                if (has_diag) atomicAdd(&possum[lrow], pos);
            }
        }
    }
    __syncthreads();
    if (tid < 64) {
        atomicAdd(&g_row[row0 + tid], rowsum[tid]);
        if (has_diag) atomicAdd(&g_pos[row0 + tid], possum[tid]);
    }

    // ---- fused finalize: last block computes the loss (R8-proven pattern).
    __threadfence();
    if (tid == 0) last_flag = (atomicAdd(cnt, 1u) == (NBLK_GEMM - 1)) ? 1u : 0u;
    __syncthreads();
    if (last_flag) {
        __threadfence();
        float v = 0.f;
        for (int i = tid; i < N_SPK; i += 512) {
            const float pos = g_pos[i];
            const float neg = g_row[i] - pos;
            v += logf(fmaxf(neg, 1e-30f)) - logf(fmaxf(pos, 1e-30f));
        }
#pragma unroll
        for (int m = 1; m < 64; m <<= 1) v += __shfl_xor(v, m, 64);
        if (lane == 0) ws2[w] = v;
        __syncthreads();
        if (tid == 0) {
            float s = 0.f;
#pragma unroll
            for (int j = 0; j < 8; ++j) s += ws2[j];
            out[0] = s * (1.f / 1024.f);
        }
    }
}

extern "C" void kernel_launch(void* const* d_in, const int* in_sizes, int n_in,
                              void* d_out, int out_size, void* d_ws, size_t ws_size,
                              hipStream_t stream) {
    const float* emb = (const float*)d_in[0];
    // d_in[1] = labels (unused; structure fixed by construction)
    const float* alpha_p = (const float*)d_in[2];
    const float* beta_p = (const float*)d_in[3];

    unsigned short* cent = (unsigned short*)d_ws;          // 1024*512 bf16 = 1 MB
    unsigned short* test = cent + (size_t)N_SPK * D;       // 16384*512 bf16 = 16 MB
    float* g_row = (float*)(test + (size_t)N_TEST_ROWS * D);
    float* g_pos = g_row + N_SPK;
    unsigned int* cnt = (unsigned int*)(g_pos + N_SPK);

    prep_kernel<<<N_SPK + N_TEST_ROWS / 4, 256, 0, stream>>>(emb, cent, test,
                                                             g_row, g_pos, cnt);

    gemm_kernel<<<NBLK_GEMM, 512, 0, stream>>>(cent, test, alpha_p, beta_p,
                                               g_row, g_pos, cnt, (float*)d_out);
}

// Round 12
// 75.140 us; speedup vs baseline: 1.5198x; 1.5198x over previous
//
#include <hip/hip_runtime.h>
#include <math.h>

#define N_SPK 1024
#define M_UTT 32
#define M_ENR 16
#define M_TEST 16
#define D 512
#define N_TEST_ROWS (N_SPK * M_TEST)   // 16384
#define NBLK_GEMM 256

// CONSOLIDATED: round-3 structure verbatim (best measured: gemm ~28.5 us,
// total 49.1 us) + fused finalize (R8/R10-proven atomic-counter pattern).
// gemm: block = 512 thr (8 waves), tile 128spk x 512test, wave = 128 x 64.
// grid = 8 x 32 = 256 blocks = 1 per CU. A (cent) panel LDS-resident
// (XOR-swizzled, staged once via global_load_lds), B (test) streamed
// L2->reg with the REQUIRED 1-deep ring (R11: removing it = 3.5x slower;
// R4: deeper = null), barrier-free K-loop.

typedef __attribute__((ext_vector_type(4))) float f32x4;
typedef __attribute__((ext_vector_type(8))) short short8;
typedef __attribute__((ext_vector_type(8))) unsigned short ushort8;

typedef const __attribute__((address_space(1))) void g_void;
typedef __attribute__((address_space(3))) void lds_void;

__device__ __forceinline__ unsigned short f2bf(float f) {
    unsigned int u = __float_as_uint(f);
    u += 0x7FFF + ((u >> 16) & 1);   // round-to-nearest-even
    return (unsigned short)(u >> 16);
}

// ---------------------------------------------------------------------------
// Kernel 1: centroids + test-row normalize; blocks [0,4) zero g_row/g_pos/cnt.
// ---------------------------------------------------------------------------
__global__ __launch_bounds__(256) void prep_kernel(const float* __restrict__ emb,
                                                   unsigned short* __restrict__ cent,
                                                   unsigned short* __restrict__ test,
                                                   float* __restrict__ g_row,
                                                   float* __restrict__ g_pos,
                                                   unsigned int* __restrict__ cnt) {
    const int b = blockIdx.x;
    const int tid = threadIdx.x;
    const int lane = tid & 63;
    const int wid = tid >> 6;

    if (b < 4) {
        g_row[b * 256 + tid] = 0.f;
        g_pos[b * 256 + tid] = 0.f;
        if (b == 0 && tid == 0) *cnt = 0u;
    }

    if (b < N_SPK) {
        const float* base = emb + (size_t)b * M_UTT * D;
        float a0 = 0.f, a1 = 0.f;
#pragma unroll
        for (int u = 0; u < M_ENR; ++u) {
            a0 += base[u * D + tid];
            a1 += base[u * D + tid + 256];
        }
        a0 *= (1.f / 16.f);
        a1 *= (1.f / 16.f);
        float ss = a0 * a0 + a1 * a1;
#pragma unroll
        for (int m = 1; m < 64; m <<= 1) ss += __shfl_xor(ss, m, 64);
        __shared__ float wss[4];
        if (lane == 0) wss[wid] = ss;
        __syncthreads();
        const float tot = wss[0] + wss[1] + wss[2] + wss[3];
        const float inv = 1.f / fmaxf(sqrtf(tot), 1e-8f);
        cent[b * D + tid] = f2bf(a0 * inv);
        cent[b * D + tid + 256] = f2bf(a1 * inv);
    } else {
        const int r = (b - N_SPK) * 4 + wid;   // test row 0..16383
        const int s = r >> 4, t = r & 15;
        const float* row = emb + ((size_t)s * M_UTT + M_ENR + t) * D;
        const f32x4* rv = (const f32x4*)row;
        const f32x4 v0 = rv[lane * 2];
        const f32x4 v1 = rv[lane * 2 + 1];
        float ss = v0[0]*v0[0] + v0[1]*v0[1] + v0[2]*v0[2] + v0[3]*v0[3]
                 + v1[0]*v1[0] + v1[1]*v1[1] + v1[2]*v1[2] + v1[3]*v1[3];
#pragma unroll
        for (int m = 1; m < 64; m <<= 1) ss += __shfl_xor(ss, m, 64);
        const float inv = 1.f / fmaxf(sqrtf(ss), 1e-8f);
        ushort8 o;
        o[0] = f2bf(v0[0] * inv); o[1] = f2bf(v0[1] * inv);
        o[2] = f2bf(v0[2] * inv); o[3] = f2bf(v0[3] * inv);
        o[4] = f2bf(v1[0] * inv); o[5] = f2bf(v1[1] * inv);
        o[6] = f2bf(v1[2] * inv); o[7] = f2bf(v1[3] * inv);
        *(ushort8*)&test[(size_t)r * D + lane * 8] = o;
    }
}

// ---------------------------------------------------------------------------
// Kernel 2: R3-structure GEMM (verbatim loop) + fused finalize tail.
// ---------------------------------------------------------------------------
__global__ __launch_bounds__(512, 1) void gemm_kernel(const unsigned short* __restrict__ A,  // cent 1024x512
                                                      const unsigned short* __restrict__ B,  // test 16384x512
                                                      const float* __restrict__ alpha_p,
                                                      const float* __restrict__ beta_p,
                                                      float* __restrict__ g_row,
                                                      float* __restrict__ g_pos,
                                                      unsigned int* __restrict__ cnt,
                                                      float* __restrict__ out) {
    __shared__ __align__(16) unsigned short As[128 * 512];   // 128 KB, swizzled
    __shared__ float rowsum[128];
    __shared__ float possum[128];
    __shared__ unsigned int last_flag;
    __shared__ float ws2[8];

    const int tid = threadIdx.x;
    const int lane = tid & 63;
    const int w = tid >> 6;          // wave 0..7, owns test cols [w*64, +64)

    const int raw = blockIdx.x;
    const int wg = (raw & 7) * 32 + (raw >> 3);   // XCD swizzle (8 x 32)
    const int bi = wg & 7;           // speaker panel (128 rows)
    const int bj = wg >> 3;          // test panel (512 cols)
    const int row0 = bi * 128, col0 = bj * 512;
    const bool has_diag = ((bj >> 2) == bi);

    // ---- stage cent panel once: LDS[r][e] = A[row0+r][ e ^ ((r&7)<<3) ]
#pragma unroll
    for (int it = 0; it < 16; ++it) {
        const int r = it * 8 + w;
        const int src = (row0 + r) * D + ((lane * 8) ^ ((r & 7) << 3));
        __builtin_amdgcn_global_load_lds((g_void*)&A[src],
                                         (lds_void*)&As[r * D], 16, 0, 0);
    }
    if (tid < 128) { rowsum[tid] = 0.f; possum[tid] = 0.f; }

    const float alpha = *alpha_p;
    const float beta = *beta_p;

    const int bcol = col0 + w * 64;
    const unsigned short* bp[4];
#pragma unroll
    for (int ni = 0; ni < 4; ++ni)
        bp[ni] = &B[(size_t)(bcol + ni * 16 + (lane & 15)) * D + (lane >> 4) * 8];

    // swizzled LDS read offset: (kk + (lane>>4)*8) ^ ((lane&7)<<3) = kk ^ hs
    const int hs = ((lane >> 4) * 8) ^ ((lane & 7) << 3);
    const int arow_base = (lane & 15) * D;

    f32x4 acc[8][4] = {};
    short8 b0[4], b1[4];

#define LOADB(dst, kk)                                              \
    {                                                               \
        _Pragma("unroll") for (int ni = 0; ni < 4; ++ni)            \
            dst[ni] = *(const short8*)(bp[ni] + (kk));              \
    }

#define STEP(bfr, kk)                                                          \
    {                                                                          \
        const int ofs_ = (kk) ^ hs;                                            \
        _Pragma("unroll") for (int mi = 0; mi < 8; ++mi) {                     \
            const short8 af_ = *(const short8*)&As[mi * 16 * D + arow_base + ofs_]; \
            _Pragma("unroll") for (int ni = 0; ni < 4; ++ni)                   \
                acc[mi][ni] = __builtin_amdgcn_mfma_f32_16x16x32_bf16(         \
                    af_, bfr[ni], acc[mi][ni], 0, 0, 0);                       \
        }                                                                      \
    }

    LOADB(b0, 0); LOADB(b1, 32);
    __syncthreads();   // A staged (drains vmcnt; b0/b1 in flight)

    for (int ko = 0; ko < D; ko += 64) {
        STEP(b0, ko);       LOADB(b0, (ko + 64) & (D - 1));   // wrap: harmless reload
        STEP(b1, ko + 32);  LOADB(b1, (ko + 96) & (D - 1));
    }
#undef LOADB
#undef STEP

    // ---- epilogue: e = exp(alpha*s + beta); row totals + diagonal sums.
    // C/D layout (16x16x32): col = lane&15, row = (lane>>4)*4 + reg   [m89]
#pragma unroll
    for (int mi = 0; mi < 8; ++mi) {
#pragma unroll
        for (int r = 0; r < 4; ++r) {
            const int lrow = mi * 16 + ((lane >> 4) << 2) + r;
            const int grow = row0 + lrow;
            float tot = 0.f, pos = 0.f;
#pragma unroll
            for (int ni = 0; ni < 4; ++ni) {
                const int gcol = bcol + ni * 16 + (lane & 15);
                const float e = __expf(fmaf(alpha, acc[mi][ni][r], beta));
                tot += e;
                if (has_diag) pos += ((gcol >> 4) == grow) ? e : 0.f;
            }
#pragma unroll
            for (int m = 1; m < 16; m <<= 1) tot += __shfl_xor(tot, m, 64);
            if (has_diag) {
#pragma unroll
                for (int m = 1; m < 16; m <<= 1) pos += __shfl_xor(pos, m, 64);
            }
            if ((lane & 15) == 0) {
                atomicAdd(&rowsum[lrow], tot);
                if (has_diag) atomicAdd(&possum[lrow], pos);
            }
        }
    }
    __syncthreads();
    if (tid < 128) {
        atomicAdd(&g_row[row0 + tid], rowsum[tid]);
        if (has_diag) atomicAdd(&g_pos[row0 + tid], possum[tid]);
    }

    // ---- fused finalize: last block computes the loss (R8/R10-proven).
    __threadfence();
    if (tid == 0) last_flag = (atomicAdd(cnt, 1u) == (NBLK_GEMM - 1)) ? 1u : 0u;
    __syncthreads();
    if (last_flag) {
        __threadfence();
        float v = 0.f;
        for (int i = tid; i < N_SPK; i += 512) {
            const float pos = g_pos[i];
            const float neg = g_row[i] - pos;
            v += logf(fmaxf(neg, 1e-30f)) - logf(fmaxf(pos, 1e-30f));
        }
#pragma unroll
        for (int m = 1; m < 64; m <<= 1) v += __shfl_xor(v, m, 64);
        if (lane == 0) ws2[w] = v;
        __syncthreads();
        if (tid == 0) {
            float s = 0.f;
#pragma unroll
            for (int j = 0; j < 8; ++j) s += ws2[j];
            out[0] = s * (1.f / 1024.f);
        }
    }
}

extern "C" void kernel_launch(void* const* d_in, const int* in_sizes, int n_in,
                              void* d_out, int out_size, void* d_ws, size_t ws_size,
                              hipStream_t stream) {
    const float* emb = (const float*)d_in[0];
    // d_in[1] = labels (unused; structure fixed by construction)
    const float* alpha_p = (const float*)d_in[2];
    const float* beta_p = (const float*)d_in[3];

    unsigned short* cent = (unsigned short*)d_ws;          // 1024*512 bf16 = 1 MB
    unsigned short* test = cent + (size_t)N_SPK * D;       // 16384*512 bf16 = 16 MB
    float* g_row = (float*)(test + (size_t)N_TEST_ROWS * D);
    float* g_pos = g_row + N_SPK;
    unsigned int* cnt = (unsigned int*)(g_pos + N_SPK);

    prep_kernel<<<N_SPK + N_TEST_ROWS / 4, 256, 0, stream>>>(emb, cent, test,
                                                             g_row, g_pos, cnt);

    gemm_kernel<<<NBLK_GEMM, 512, 0, stream>>>(cent, test, alpha_p, beta_p,
                                               g_row, g_pos, cnt, (float*)d_out);
}

// Round 13
// 59.446 us; speedup vs baseline: 1.9211x; 1.2640x over previous
//
#include <hip/hip_runtime.h>
#include <math.h>

#define N_SPK 1024
#define M_UTT 32
#define M_ENR 16
#define M_TEST 16
#define D 512
#define N_TEST_ROWS (N_SPK * M_TEST)   // 16384

// gemm: block = 512 thr (8 waves), tile 64spk x 512test, wave = 64 x 64
// (acc[4][4] = 64 AGPR, ni=4 = minimal LDS-read floor). As = 64 KB ->
// 2 blocks/CU; (512,4) caps unified regs at 128 -> 4 waves/SIMD.
// 1-deep B ring (R11 proved necessary; R4 proved deeper is null) with a
// LEAN register budget (~120 <= 128; R5's 4-deep ring at this cap spilled).
// Wave-uniform B base -> SGPR; per-lane 32-bit offsets. No fused tail
// (R9/R12: tail fusion = 2x regression via regalloc).

typedef __attribute__((ext_vector_type(4))) float f32x4;
typedef __attribute__((ext_vector_type(8))) short short8;
typedef __attribute__((ext_vector_type(8))) unsigned short ushort8;

typedef const __attribute__((address_space(1))) void g_void;
typedef __attribute__((address_space(3))) void lds_void;

__device__ __forceinline__ unsigned short f2bf(float f) {
    unsigned int u = __float_as_uint(f);
    u += 0x7FFF + ((u >> 16) & 1);   // round-to-nearest-even
    return (unsigned short)(u >> 16);
}

// ---------------------------------------------------------------------------
// Kernel 1: centroids + test-row normalize; blocks [0,4) also zero g_row/g_pos.
// (R3-verbatim)
// ---------------------------------------------------------------------------
__global__ __launch_bounds__(256) void prep_kernel(const float* __restrict__ emb,
                                                   unsigned short* __restrict__ cent,
                                                   unsigned short* __restrict__ test,
                                                   float* __restrict__ g_row,
                                                   float* __restrict__ g_pos) {
    const int b = blockIdx.x;
    const int tid = threadIdx.x;
    const int lane = tid & 63;
    const int wid = tid >> 6;

    if (b < 4) {
        g_row[b * 256 + tid] = 0.f;
        g_pos[b * 256 + tid] = 0.f;
    }

    if (b < N_SPK) {
        const float* base = emb + (size_t)b * M_UTT * D;
        float a0 = 0.f, a1 = 0.f;
#pragma unroll
        for (int u = 0; u < M_ENR; ++u) {
            a0 += base[u * D + tid];
            a1 += base[u * D + tid + 256];
        }
        a0 *= (1.f / 16.f);
        a1 *= (1.f / 16.f);
        float ss = a0 * a0 + a1 * a1;
#pragma unroll
        for (int m = 1; m < 64; m <<= 1) ss += __shfl_xor(ss, m, 64);
        __shared__ float wss[4];
        if (lane == 0) wss[wid] = ss;
        __syncthreads();
        const float tot = wss[0] + wss[1] + wss[2] + wss[3];
        const float inv = 1.f / fmaxf(sqrtf(tot), 1e-8f);
        cent[b * D + tid] = f2bf(a0 * inv);
        cent[b * D + tid + 256] = f2bf(a1 * inv);
    } else {
        const int r = (b - N_SPK) * 4 + wid;   // test row 0..16383
        const int s = r >> 4, t = r & 15;
        const float* row = emb + ((size_t)s * M_UTT + M_ENR + t) * D;
        const f32x4* rv = (const f32x4*)row;
        const f32x4 v0 = rv[lane * 2];
        const f32x4 v1 = rv[lane * 2 + 1];
        float ss = v0[0]*v0[0] + v0[1]*v0[1] + v0[2]*v0[2] + v0[3]*v0[3]
                 + v1[0]*v1[0] + v1[1]*v1[1] + v1[2]*v1[2] + v1[3]*v1[3];
#pragma unroll
        for (int m = 1; m < 64; m <<= 1) ss += __shfl_xor(ss, m, 64);
        const float inv = 1.f / fmaxf(sqrtf(ss), 1e-8f);
        ushort8 o;
        o[0] = f2bf(v0[0] * inv); o[1] = f2bf(v0[1] * inv);
        o[2] = f2bf(v0[2] * inv); o[3] = f2bf(v0[3] * inv);
        o[4] = f2bf(v1[0] * inv); o[5] = f2bf(v1[1] * inv);
        o[6] = f2bf(v1[2] * inv); o[7] = f2bf(v1[3] * inv);
        *(ushort8*)&test[(size_t)r * D + lane * 8] = o;
    }
}

// ---------------------------------------------------------------------------
// Kernel 2: 64x512 tile, 2 blocks/CU, 4 waves/SIMD, 1-deep lean B ring.
// ---------------------------------------------------------------------------
__global__ __launch_bounds__(512, 4) void gemm_kernel(const unsigned short* __restrict__ A,  // cent 1024x512
                                                      const unsigned short* __restrict__ B,  // test 16384x512
                                                      const float* __restrict__ alpha_p,
                                                      const float* __restrict__ beta_p,
                                                      float* __restrict__ g_row,
                                                      float* __restrict__ g_pos) {
    __shared__ __align__(16) unsigned short As[64 * 512];   // 64 KB, swizzled
    __shared__ float rowsum[64];
    __shared__ float possum[64];

    const int tid = threadIdx.x;
    const int lane = tid & 63;
    const int w = tid >> 6;          // wave 0..7, owns test cols [w*64, +64)
    const int l15 = lane & 15;

    // XCD swizzle: 512 blocks = 8 XCDs x 64; each XCD: 4 bj panels (2MB) + A (1MB).
    const int raw = blockIdx.x;
    const int wg = (raw & 7) * 64 + (raw >> 3);
    const int bi = wg & 15;          // 16 speaker panels (64 rows)
    const int bj = wg >> 4;          // 32 test panels (512 cols)
    const int row0 = bi * 64, col0 = bj * 512;
    const bool has_diag = ((bj >> 1) == bi);

    // ---- stage cent panel once: LDS[r][e] = A[row0+r][ e ^ ((r&7)<<3) ]
    // (R11-verbatim, correctness-verified)
#pragma unroll
    for (int it = 0; it < 8; ++it) {
        const int r = it * 8 + w;    // r&7 == w (wave-uniform swizzle const)
        const int src = (row0 + r) * D + ((lane * 8) ^ ((r & 7) << 3));
        __builtin_amdgcn_global_load_lds((g_void*)&A[src],
                                         (lds_void*)&As[r * D], 16, 0, 0);
    }
    if (tid < 64) { rowsum[tid] = 0.f; possum[tid] = 0.f; }

    const float alpha = *alpha_p;
    const float beta = *beta_p;

    // Wave-uniform B base (SGPR) + per-lane 32-bit element offsets (lean regs).
    const int bcol = col0 + w * 64;
    const unsigned short* bbase = B + (size_t)bcol * D;   // wave-uniform
    int boff[4];
#pragma unroll
    for (int ni = 0; ni < 4; ++ni)
        boff[ni] = (ni * 16 + l15) * D + (lane >> 4) * 8;

    // swizzled LDS read offset: (kk + (lane>>4)*8) ^ ((lane&7)<<3) = kk ^ hs
    const int hs = ((lane >> 4) * 8) ^ ((lane & 7) << 3);
    const int arow_base = l15 * D;

    f32x4 acc[4][4] = {};
    short8 b0[4], b1[4];

#define LOADB(dst, kk)                                              \
    {                                                               \
        _Pragma("unroll") for (int ni = 0; ni < 4; ++ni)            \
            dst[ni] = *(const short8*)(bbase + boff[ni] + (kk));    \
    }

#define STEP(bfr, kk)                                                          \
    {                                                                          \
        const int ofs_ = (kk) ^ hs;                                            \
        _Pragma("unroll") for (int mi = 0; mi < 4; ++mi) {                     \
            const short8 af_ = *(const short8*)&As[mi * 16 * D + arow_base + ofs_]; \
            _Pragma("unroll") for (int ni = 0; ni < 4; ++ni)                   \
                acc[mi][ni] = __builtin_amdgcn_mfma_f32_16x16x32_bf16(         \
                    af_, bfr[ni], acc[mi][ni], 0, 0, 0);                       \
        }                                                                      \
    }

    LOADB(b0, 0); LOADB(b1, 32);
    __syncthreads();   // A staged (drains vmcnt; b0/b1 in flight)

    for (int ko = 0; ko < D; ko += 64) {
        STEP(b0, ko);       LOADB(b0, (ko + 64) & (D - 1));   // wrap: harmless reload
        STEP(b1, ko + 32);  LOADB(b1, (ko + 96) & (D - 1));
    }
#undef LOADB
#undef STEP

    // ---- epilogue: e = exp(alpha*s + beta); row totals + diagonal sums.
    // C/D layout (16x16x32): col = lane&15, row = (lane>>4)*4 + reg   [m89]
#pragma unroll
    for (int mi = 0; mi < 4; ++mi) {
#pragma unroll
        for (int r = 0; r < 4; ++r) {
            const int lrow = mi * 16 + ((lane >> 4) << 2) + r;
            const int grow = row0 + lrow;
            float tot = 0.f, pos = 0.f;
#pragma unroll
            for (int ni = 0; ni < 4; ++ni) {
                const int gcol = bcol + ni * 16 + l15;
                const float e = __expf(fmaf(alpha, acc[mi][ni][r], beta));
                tot += e;
                if (has_diag) pos += ((gcol >> 4) == grow) ? e : 0.f;
            }
#pragma unroll
            for (int m = 1; m < 16; m <<= 1) tot += __shfl_xor(tot, m, 64);
            if (has_diag) {
#pragma unroll
                for (int m = 1; m < 16; m <<= 1) pos += __shfl_xor(pos, m, 64);
            }
            if (l15 == 0) {
                atomicAdd(&rowsum[lrow], tot);
                if (has_diag) atomicAdd(&possum[lrow], pos);
            }
        }
    }
    __syncthreads();
    if (tid < 64) {
        atomicAdd(&g_row[row0 + tid], rowsum[tid]);
        if (has_diag) atomicAdd(&g_pos[row0 + tid], possum[tid]);
    }
}

// ---------------------------------------------------------------------------
// Kernel 3: loss = mean(log(tot - pos) - log(pos)) — shfl-based, 1 barrier.
// ---------------------------------------------------------------------------
__global__ __launch_bounds__(1024) void finalize_kernel(const float* __restrict__ g_row,
                                                        const float* __restrict__ g_pos,
                                                        float* __restrict__ out) {
    __shared__ float wsum[16];
    const int i = threadIdx.x;
    const int lane = i & 63, wid = i >> 6;
    const float pos = g_pos[i];
    const float neg = g_row[i] - pos;
    float v = logf(fmaxf(neg, 1e-30f)) - logf(fmaxf(pos, 1e-30f));
#pragma unroll
    for (int m = 1; m < 64; m <<= 1) v += __shfl_xor(v, m, 64);
    if (lane == 0) wsum[wid] = v;
    __syncthreads();
    if (i < 64) {
        float s = (i < 16) ? wsum[i] : 0.f;
#pragma unroll
        for (int m = 1; m < 16; m <<= 1) s += __shfl_xor(s, m, 64);
        if (i == 0) out[0] = s * (1.f / 1024.f);
    }
}

extern "C" void kernel_launch(void* const* d_in, const int* in_sizes, int n_in,
                              void* d_out, int out_size, void* d_ws, size_t ws_size,
                              hipStream_t stream) {
    const float* emb = (const float*)d_in[0];
    // d_in[1] = labels (unused; structure fixed by construction)
    const float* alpha_p = (const float*)d_in[2];
    const float* beta_p = (const float*)d_in[3];

    unsigned short* cent = (unsigned short*)d_ws;          // 1024*512 bf16 = 1 MB
    unsigned short* test = cent + (size_t)N_SPK * D;       // 16384*512 bf16 = 16 MB
    float* g_row = (float*)(test + (size_t)N_TEST_ROWS * D);
    float* g_pos = g_row + N_SPK;

    prep_kernel<<<N_SPK + N_TEST_ROWS / 4, 256, 0, stream>>>(emb, cent, test, g_row, g_pos);

    gemm_kernel<<<512, 512, 0, stream>>>(cent, test, alpha_p, beta_p, g_row, g_pos);

    finalize_kernel<<<1, 1024, 0, stream>>>(g_row, g_pos, (float*)d_out);
}

// Round 14
// 46.440 us; speedup vs baseline: 2.4591x; 1.2801x over previous
//
#include <hip/hip_runtime.h>
#include <math.h>

#define N_SPK 1024
#define M_UTT 32
#define M_ENR 16
#define M_TEST 16
#define D 512
#define N_TEST_ROWS (N_SPK * M_TEST)   // 16384

// gemm: 8-phase counted-vmcnt schedule (T3+T4+T2+T5), tile 256spk x 256test,
// BK=64 (8 K-tiles, 2 per iteration), 8 waves (2M x 4N), wave tile 128x64
// (acc[8][4] = 128 AGPR, same as proven R3). LDS: double-buffered K-tiles,
// A[2][256][64] + B[2][256][64] = 128 KB, XOR-swizzled (pre-swizzled global
// source, linear gload_lds dest). Loads stay in flight ACROSS raw s_barriers;
// vmcnt(4) only at phases 4 and 8. 2 waves/SIMD (occupancy >2 proven
// unreachable: 5 spill failures R5/R8/R9/R10/R13).

typedef __attribute__((ext_vector_type(4))) float f32x4;
typedef __attribute__((ext_vector_type(8))) short short8;
typedef __attribute__((ext_vector_type(8))) unsigned short ushort8;

typedef const __attribute__((address_space(1))) void g_void;
typedef __attribute__((address_space(3))) void lds_void;

__device__ __forceinline__ unsigned short f2bf(float f) {
    unsigned int u = __float_as_uint(f);
    u += 0x7FFF + ((u >> 16) & 1);   // round-to-nearest-even
    return (unsigned short)(u >> 16);
}

// ---------------------------------------------------------------------------
// Kernel 1: centroids + test-row normalize; blocks [0,4) also zero g_row/g_pos.
// (R3-verbatim, proven)
// ---------------------------------------------------------------------------
__global__ __launch_bounds__(256) void prep_kernel(const float* __restrict__ emb,
                                                   unsigned short* __restrict__ cent,
                                                   unsigned short* __restrict__ test,
                                                   float* __restrict__ g_row,
                                                   float* __restrict__ g_pos) {
    const int b = blockIdx.x;
    const int tid = threadIdx.x;
    const int lane = tid & 63;
    const int wid = tid >> 6;

    if (b < 4) {
        g_row[b * 256 + tid] = 0.f;
        g_pos[b * 256 + tid] = 0.f;
    }

    if (b < N_SPK) {
        const float* base = emb + (size_t)b * M_UTT * D;
        float a0 = 0.f, a1 = 0.f;
#pragma unroll
        for (int u = 0; u < M_ENR; ++u) {
            a0 += base[u * D + tid];
            a1 += base[u * D + tid + 256];
        }
        a0 *= (1.f / 16.f);
        a1 *= (1.f / 16.f);
        float ss = a0 * a0 + a1 * a1;
#pragma unroll
        for (int m = 1; m < 64; m <<= 1) ss += __shfl_xor(ss, m, 64);
        __shared__ float wss[4];
        if (lane == 0) wss[wid] = ss;
        __syncthreads();
        const float tot = wss[0] + wss[1] + wss[2] + wss[3];
        const float inv = 1.f / fmaxf(sqrtf(tot), 1e-8f);
        cent[b * D + tid] = f2bf(a0 * inv);
        cent[b * D + tid + 256] = f2bf(a1 * inv);
    } else {
        const int r = (b - N_SPK) * 4 + wid;   // test row 0..16383
        const int s = r >> 4, t = r & 15;
        const float* row = emb + ((size_t)s * M_UTT + M_ENR + t) * D;
        const f32x4* rv = (const f32x4*)row;
        const f32x4 v0 = rv[lane * 2];
        const f32x4 v1 = rv[lane * 2 + 1];
        float ss = v0[0]*v0[0] + v0[1]*v0[1] + v0[2]*v0[2] + v0[3]*v0[3]
                 + v1[0]*v1[0] + v1[1]*v1[1] + v1[2]*v1[2] + v1[3]*v1[3];
#pragma unroll
        for (int m = 1; m < 64; m <<= 1) ss += __shfl_xor(ss, m, 64);
        const float inv = 1.f / fmaxf(sqrtf(ss), 1e-8f);
        ushort8 o;
        o[0] = f2bf(v0[0] * inv); o[1] = f2bf(v0[1] * inv);
        o[2] = f2bf(v0[2] * inv); o[3] = f2bf(v0[3] * inv);
        o[4] = f2bf(v1[0] * inv); o[5] = f2bf(v1[1] * inv);
        o[6] = f2bf(v1[2] * inv); o[7] = f2bf(v1[3] * inv);
        *(ushort8*)&test[(size_t)r * D + lane * 8] = o;
    }
}

// ---------------------------------------------------------------------------
// Kernel 2: 8-phase GEMM + fused exp/row-sum epilogue.
// ---------------------------------------------------------------------------
__global__ __launch_bounds__(512) void gemm_kernel(const unsigned short* __restrict__ A,  // cent 1024x512
                                                   const unsigned short* __restrict__ B,  // test 16384x512
                                                   const float* __restrict__ alpha_p,
                                                   const float* __restrict__ beta_p,
                                                   float* __restrict__ g_row,
                                                   float* __restrict__ g_pos) {
    __shared__ __align__(16) unsigned short AsL[2 * 256 * 64];   // 64 KB
    __shared__ __align__(16) unsigned short BsL[2 * 256 * 64];   // 64 KB
    __shared__ float rowsum[256];
    __shared__ float possum[256];

    const int tid = threadIdx.x;
    const int lane = tid & 63;
    const int w = tid >> 6;          // wave 0..7
    const int wr = w >> 2;           // 0..1  M-half (128 speaker rows)
    const int wc = w & 3;            // 0..3  N-quarter (64 test cols)
    const int l15 = lane & 15;

    // XCD swizzle: 256 blocks = 8 XCDs x 32 -> each XCD: 8 bj panels (2 MB B) + A.
    const int raw = blockIdx.x;
    const int wg = (raw & 7) * 32 + (raw >> 3);
    const int bi = wg & 3;           // 4 speaker panels (256 rows)
    const int bj = wg >> 2;          // 64 test panels (256 cols)
    const int row0 = bi * 256, col0 = bj * 256;
    const bool has_diag = ((bj >> 4) == bi);

    // staging swizzle: LDS[row][slot s] = global slot s ^ (row&7), 16B slots
    const int sw8 = 8 * ((lane & 7) ^ (lane >> 3));   // source elem offset
    // read swizzle: elem ofs = (kk + (lane>>4)*8) ^ ((lane&7)<<3) = kk ^ hs
    const int hs = ((lane >> 4) * 8) ^ ((lane & 7) << 3);

    const float alpha = *alpha_p;
    const float beta = *beta_p;

    // ---- stage one half-tile: OP 0=A(cent rows) 1=B(test rows), HF in {0,1},
    //      BUF in {0,1}, KT = K-tile index. 2 gload_lds per thread.
#define STAGE_H(OP, BUF, HF, KT)                                               \
    {                                                                          \
        const unsigned short* gb_ = (OP) ? B : A;                              \
        const int r0_ = ((OP) ? col0 : row0) + (HF) * 128;                     \
        _Pragma("unroll") for (int i_ = 0; i_ < 2; ++i_) {                     \
            const int rl_ = i_ * 64 + w * 8 + (lane >> 3);                     \
            unsigned short* lb_ = ((OP) ? BsL : AsL) +                         \
                (BUF) * 16384 + ((HF) * 128 + i_ * 64 + w * 8) * 64;           \
            __builtin_amdgcn_global_load_lds(                                  \
                (g_void*)&gb_[(size_t)(r0_ + rl_) * D + (KT) * 64 + sw8],      \
                (lds_void*)lb_, 16, 0, 0);                                     \
        }                                                                      \
    }

    // ---- ds-read register subtiles (b128, swizzled)
#define LDA8(BUF, MIH)                                                         \
    _Pragma("unroll") for (int j_ = 0; j_ < 4; ++j_) {                         \
        const int row_ = wr * 128 + ((MIH) * 4 + j_) * 16 + l15;               \
        af[j_ * 2]     = *(const short8*)&AsL[(BUF) * 16384 + row_ * 64 + (0 ^ hs)];  \
        af[j_ * 2 + 1] = *(const short8*)&AsL[(BUF) * 16384 + row_ * 64 + (32 ^ hs)]; \
    }
#define LDB4(DST, BUF, NIH)                                                    \
    _Pragma("unroll") for (int n_ = 0; n_ < 2; ++n_) {                         \
        const int row_ = wc * 64 + ((NIH) * 2 + n_) * 16 + l15;                \
        DST[n_ * 2]     = *(const short8*)&BsL[(BUF) * 16384 + row_ * 64 + (0 ^ hs)];  \
        DST[n_ * 2 + 1] = *(const short8*)&BsL[(BUF) * 16384 + row_ * 64 + (32 ^ hs)]; \
    }

    // ---- one C-quadrant x K=64: 16 MFMA, setprio-wrapped (T5)
#define MM(BF, MIH, NIH)                                                       \
    {                                                                          \
        __builtin_amdgcn_s_setprio(1);                                         \
        _Pragma("unroll") for (int j_ = 0; j_ < 4; ++j_)                       \
            _Pragma("unroll") for (int n_ = 0; n_ < 2; ++n_)                   \
                _Pragma("unroll") for (int k_ = 0; k_ < 2; ++k_)               \
                    acc[(MIH) * 4 + j_][(NIH) * 2 + n_] =                      \
                        __builtin_amdgcn_mfma_f32_16x16x32_bf16(               \
                            af[j_ * 2 + k_], BF[n_ * 2 + k_],                  \
                            acc[(MIH) * 4 + j_][(NIH) * 2 + n_], 0, 0, 0);     \
        __builtin_amdgcn_s_setprio(0);                                         \
    }

#define VM4 asm volatile("s_waitcnt vmcnt(4)" ::: "memory")
#define VM0 asm volatile("s_waitcnt vmcnt(0)" ::: "memory")
#define BAR __builtin_amdgcn_s_barrier()

    f32x4 acc[8][4] = {};
    short8 af[8], bf0[4], bf1[4];

    // ---- prologue: T0 full (4 halves) + T1-B (2 halves); confirm T0.
    STAGE_H(0, 0, 0, 0) STAGE_H(0, 0, 1, 0) STAGE_H(1, 0, 0, 0) STAGE_H(1, 0, 1, 0)
    STAGE_H(1, 1, 0, 1) STAGE_H(1, 1, 1, 1)
    if (tid < 256) { rowsum[tid] = 0.f; possum[tid] = 0.f; }
    VM4;                       // T0's 8 loads landed; T1-B (4) in flight
    BAR;

    // ---- main loop: 4 iterations x 8 phases, 2 K-tiles each. Stages:
    // ph1,2: A(T1)->buf1 | ph3,4: B(T2)->buf0 | ph5,6: A(T2)->buf0 | ph7,8: B(T3)->buf1
#pragma unroll
    for (int it = 0; it < 4; ++it) {
        // phase 1: reads A0+B0 of buf0 (12)
        LDA8(0, 0) LDB4(bf0, 0, 0)
        STAGE_H(0, 1, 0, 2 * it + 1)
        BAR; MM(bf0, 0, 0) BAR;
        // phase 2: reads B1 of buf0 (4)
        LDB4(bf1, 0, 1)
        STAGE_H(0, 1, 1, 2 * it + 1)
        BAR; MM(bf1, 0, 1) BAR;
        // phase 3: reads A1 of buf0 (8)
        LDA8(0, 1)
        if (it < 3) STAGE_H(1, 0, 0, 2 * it + 2)
        BAR; MM(bf1, 1, 1) BAR;
        // phase 4: no reads; vmcnt gate -> T1 fully landed
        if (it < 3) { STAGE_H(1, 0, 1, 2 * it + 2) VM4; } else { VM0; }
        BAR; MM(bf0, 1, 0) BAR;
        // phase 5: reads A0+B0 of buf1 (12)
        LDA8(1, 0) LDB4(bf0, 1, 0)
        if (it < 3) STAGE_H(0, 0, 0, 2 * it + 2)
        BAR; MM(bf0, 0, 0) BAR;
        // phase 6: reads B1 of buf1 (4)
        LDB4(bf1, 1, 1)
        if (it < 3) STAGE_H(0, 0, 1, 2 * it + 2)
        BAR; MM(bf1, 0, 1) BAR;
        // phase 7: reads A1 of buf1 (8)
        LDA8(1, 1)
        if (it < 3) STAGE_H(1, 1, 0, 2 * it + 3)
        BAR; MM(bf1, 1, 1) BAR;
        // phase 8: no reads; vmcnt gate -> T2 fully landed
        if (it < 3) { STAGE_H(1, 1, 1, 2 * it + 3) VM4; }
        BAR; MM(bf0, 1, 0) BAR;
    }
#undef STAGE_H
#undef LDA8
#undef LDB4
#undef MM
#undef VM4
#undef VM0
#undef BAR

    // ---- epilogue: e = exp(alpha*s + beta); row totals + diagonal sums.
    // C/D layout (16x16x32): col = lane&15, row = (lane>>4)*4 + reg   [m89]
    const int bcol = col0 + wc * 64;
#pragma unroll
    for (int mi = 0; mi < 8; ++mi) {
#pragma unroll
        for (int r = 0; r < 4; ++r) {
            const int lrow = wr * 128 + mi * 16 + ((lane >> 4) << 2) + r;
            const int grow = row0 + lrow;
            float tot = 0.f, pos = 0.f;
#pragma unroll
            for (int ni = 0; ni < 4; ++ni) {
                const int gcol = bcol + ni * 16 + l15;
                const float e = __expf(fmaf(alpha, acc[mi][ni][r], beta));
                tot += e;
                if (has_diag) pos += ((gcol >> 4) == grow) ? e : 0.f;
            }
#pragma unroll
            for (int m = 1; m < 16; m <<= 1) tot += __shfl_xor(tot, m, 64);
            if (has_diag) {
#pragma unroll
                for (int m = 1; m < 16; m <<= 1) pos += __shfl_xor(pos, m, 64);
            }
            if (l15 == 0) {
                atomicAdd(&rowsum[lrow], tot);
                if (has_diag) atomicAdd(&possum[lrow], pos);
            }
        }
    }
    __syncthreads();
    if (tid < 256) {
        atomicAdd(&g_row[row0 + tid], rowsum[tid]);
        if (has_diag) atomicAdd(&g_pos[row0 + tid], possum[tid]);
    }
}

// ---------------------------------------------------------------------------
// Kernel 3: loss = mean(log(tot - pos) - log(pos)) — shfl-based, 1 barrier.
// ---------------------------------------------------------------------------
__global__ __launch_bounds__(1024) void finalize_kernel(const float* __restrict__ g_row,
                                                        const float* __restrict__ g_pos,
                                                        float* __restrict__ out) {
    __shared__ float wsum[16];
    const int i = threadIdx.x;
    const int lane = i & 63, wid = i >> 6;
    const float pos = g_pos[i];
    const float neg = g_row[i] - pos;
    float v = logf(fmaxf(neg, 1e-30f)) - logf(fmaxf(pos, 1e-30f));
#pragma unroll
    for (int m = 1; m < 64; m <<= 1) v += __shfl_xor(v, m, 64);
    if (lane == 0) wsum[wid] = v;
    __syncthreads();
    if (i < 64) {
        float s = (i < 16) ? wsum[i] : 0.f;
#pragma unroll
        for (int m = 1; m < 16; m <<= 1) s += __shfl_xor(s, m, 64);
        if (i == 0) out[0] = s * (1.f / 1024.f);
    }
}

extern "C" void kernel_launch(void* const* d_in, const int* in_sizes, int n_in,
                              void* d_out, int out_size, void* d_ws, size_t ws_size,
                              hipStream_t stream) {
    const float* emb = (const float*)d_in[0];
    // d_in[1] = labels (unused; structure fixed by construction)
    const float* alpha_p = (const float*)d_in[2];
    const float* beta_p = (const float*)d_in[3];

    unsigned short* cent = (unsigned short*)d_ws;          // 1024*512 bf16 = 1 MB
    unsigned short* test = cent + (size_t)N_SPK * D;       // 16384*512 bf16 = 16 MB
    float* g_row = (float*)(test + (size_t)N_TEST_ROWS * D);
    float* g_pos = g_row + N_SPK;

    prep_kernel<<<N_SPK + N_TEST_ROWS / 4, 256, 0, stream>>>(emb, cent, test, g_row, g_pos);

    gemm_kernel<<<256, 512, 0, stream>>>(cent, test, alpha_p, beta_p, g_row, g_pos);

    finalize_kernel<<<1, 1024, 0, stream>>>(g_row, g_pos, (float*)d_out);
}

// Round 15
// 40.497 us; speedup vs baseline: 2.8200x; 1.1467x over previous
//
#include <hip/hip_runtime.h>
#include <math.h>

#define N_SPK 1024
#define M_UTT 32
#define M_ENR 16
#define M_TEST 16
#define D 512
#define N_TEST_ROWS (N_SPK * M_TEST)   // 16384

// gemm: 8-phase counted-vmcnt schedule (T3+T4+T2+T5), tile 256spk x 256test,
// BK=64 (8 K-tiles, 2/iter), 8 waves (2M x 4N), wave tile 128x64
// (acc[8][4] = 128 AGPR). LDS dbuf A/B K-tiles (128 KB), XOR-swizzled via
// pre-swizzled global source. Loads in flight ACROSS raw s_barriers;
// vmcnt(4) gates at phases 4/8 only. 2 waves/SIMD.
// NEW this round: MFMA operands swapped (mfma(bf,af) = D-transpose) so the
// speaker axis lands on lane&15 -> per-speaker reduction = 16 VALU adds +
// 2 shuffles per mi (was 4 shuffles per (mi,r)); prep centroid float2 loads.

typedef __attribute__((ext_vector_type(4))) float f32x4;
typedef __attribute__((ext_vector_type(8))) short short8;
typedef __attribute__((ext_vector_type(8))) unsigned short ushort8;

typedef const __attribute__((address_space(1))) void g_void;
typedef __attribute__((address_space(3))) void lds_void;

__device__ __forceinline__ unsigned short f2bf(float f) {
    unsigned int u = __float_as_uint(f);
    u += 0x7FFF + ((u >> 16) & 1);   // round-to-nearest-even
    return (unsigned short)(u >> 16);
}

// ---------------------------------------------------------------------------
// Kernel 1: centroids + test-row normalize; blocks [0,4) also zero g_row/g_pos.
// Centroid path: float2 loads (8 B/lane, G13; proven in R8/R9).
// ---------------------------------------------------------------------------
__global__ __launch_bounds__(256) void prep_kernel(const float* __restrict__ emb,
                                                   unsigned short* __restrict__ cent,
                                                   unsigned short* __restrict__ test,
                                                   float* __restrict__ g_row,
                                                   float* __restrict__ g_pos) {
    const int b = blockIdx.x;
    const int tid = threadIdx.x;
    const int lane = tid & 63;
    const int wid = tid >> 6;

    if (b < 4) {
        g_row[b * 256 + tid] = 0.f;
        g_pos[b * 256 + tid] = 0.f;
    }

    if (b < N_SPK) {
        const float2* base2 = (const float2*)(emb + (size_t)b * M_UTT * D);
        float a0 = 0.f, a1 = 0.f;
#pragma unroll
        for (int u = 0; u < M_ENR; ++u) {
            const float2 v = base2[u * 256 + tid];   // cols 2tid, 2tid+1
            a0 += v.x; a1 += v.y;
        }
        a0 *= (1.f / 16.f);
        a1 *= (1.f / 16.f);
        float ss = a0 * a0 + a1 * a1;
#pragma unroll
        for (int m = 1; m < 64; m <<= 1) ss += __shfl_xor(ss, m, 64);
        __shared__ float wss[4];
        if (lane == 0) wss[wid] = ss;
        __syncthreads();
        const float tot = wss[0] + wss[1] + wss[2] + wss[3];
        const float inv = 1.f / fmaxf(sqrtf(tot), 1e-8f);
        ushort2 o2;
        o2.x = f2bf(a0 * inv);
        o2.y = f2bf(a1 * inv);
        *(ushort2*)&cent[b * D + 2 * tid] = o2;
    } else {
        const int r = (b - N_SPK) * 4 + wid;   // test row 0..16383
        const int s = r >> 4, t = r & 15;
        const float* row = emb + ((size_t)s * M_UTT + M_ENR + t) * D;
        const f32x4* rv = (const f32x4*)row;
        const f32x4 v0 = rv[lane * 2];
        const f32x4 v1 = rv[lane * 2 + 1];
        float ss = v0[0]*v0[0] + v0[1]*v0[1] + v0[2]*v0[2] + v0[3]*v0[3]
                 + v1[0]*v1[0] + v1[1]*v1[1] + v1[2]*v1[2] + v1[3]*v1[3];
#pragma unroll
        for (int m = 1; m < 64; m <<= 1) ss += __shfl_xor(ss, m, 64);
        const float inv = 1.f / fmaxf(sqrtf(ss), 1e-8f);
        ushort8 o;
        o[0] = f2bf(v0[0] * inv); o[1] = f2bf(v0[1] * inv);
        o[2] = f2bf(v0[2] * inv); o[3] = f2bf(v0[3] * inv);
        o[4] = f2bf(v1[0] * inv); o[5] = f2bf(v1[1] * inv);
        o[6] = f2bf(v1[2] * inv); o[7] = f2bf(v1[3] * inv);
        *(ushort8*)&test[(size_t)r * D + lane * 8] = o;
    }
}

// ---------------------------------------------------------------------------
// Kernel 2: 8-phase GEMM, swapped-operand epilogue.
// ---------------------------------------------------------------------------
__global__ __launch_bounds__(512) void gemm_kernel(const unsigned short* __restrict__ A,  // cent 1024x512
                                                   const unsigned short* __restrict__ B,  // test 16384x512
                                                   const float* __restrict__ alpha_p,
                                                   const float* __restrict__ beta_p,
                                                   float* __restrict__ g_row,
                                                   float* __restrict__ g_pos) {
    __shared__ __align__(16) unsigned short AsL[2 * 256 * 64];   // 64 KB
    __shared__ __align__(16) unsigned short BsL[2 * 256 * 64];   // 64 KB
    __shared__ float rowsum[256];
    __shared__ float possum[256];

    const int tid = threadIdx.x;
    const int lane = tid & 63;
    const int w = tid >> 6;          // wave 0..7
    const int wr = w >> 2;           // 0..1  M-half (128 speaker rows)
    const int wc = w & 3;            // 0..3  N-quarter (64 test cols)
    const int l15 = lane & 15;

    // XCD swizzle: 256 blocks = 8 XCDs x 32 -> each XCD: 8 bj panels (2 MB B) + A.
    const int raw = blockIdx.x;
    const int wg = (raw & 7) * 32 + (raw >> 3);
    const int bi = wg & 3;           // 4 speaker panels (256 rows)
    const int bj = wg >> 2;          // 64 test panels (256 cols)
    const int row0 = bi * 256, col0 = bj * 256;
    const bool has_diag = ((bj >> 4) == bi);

    // staging swizzle: LDS[row][slot s] = global slot s ^ (row&7), 16B slots
    const int sw8 = 8 * ((lane & 7) ^ (lane >> 3));   // source elem offset
    // read swizzle: elem ofs = (kk + (lane>>4)*8) ^ ((lane&7)<<3) = kk ^ hs
    const int hs = ((lane >> 4) * 8) ^ ((lane & 7) << 3);

    const float alpha = *alpha_p;
    const float beta = *beta_p;

#define STAGE_H(OP, BUF, HF, KT)                                               \
    {                                                                          \
        const unsigned short* gb_ = (OP) ? B : A;                              \
        const int r0_ = ((OP) ? col0 : row0) + (HF) * 128;                     \
        _Pragma("unroll") for (int i_ = 0; i_ < 2; ++i_) {                     \
            const int rl_ = i_ * 64 + w * 8 + (lane >> 3);                     \
            unsigned short* lb_ = ((OP) ? BsL : AsL) +                         \
                (BUF) * 16384 + ((HF) * 128 + i_ * 64 + w * 8) * 64;           \
            __builtin_amdgcn_global_load_lds(                                  \
                (g_void*)&gb_[(size_t)(r0_ + rl_) * D + (KT) * 64 + sw8],      \
                (lds_void*)lb_, 16, 0, 0);                                     \
        }                                                                      \
    }

#define LDA8(BUF, MIH)                                                         \
    _Pragma("unroll") for (int j_ = 0; j_ < 4; ++j_) {                         \
        const int row_ = wr * 128 + ((MIH) * 4 + j_) * 16 + l15;               \
        af[j_ * 2]     = *(const short8*)&AsL[(BUF) * 16384 + row_ * 64 + (0 ^ hs)];  \
        af[j_ * 2 + 1] = *(const short8*)&AsL[(BUF) * 16384 + row_ * 64 + (32 ^ hs)]; \
    }
#define LDB4(DST, BUF, NIH)                                                    \
    _Pragma("unroll") for (int n_ = 0; n_ < 2; ++n_) {                         \
        const int row_ = wc * 64 + ((NIH) * 2 + n_) * 16 + l15;                \
        DST[n_ * 2]     = *(const short8*)&BsL[(BUF) * 16384 + row_ * 64 + (0 ^ hs)];  \
        DST[n_ * 2 + 1] = *(const short8*)&BsL[(BUF) * 16384 + row_ * 64 + (32 ^ hs)]; \
    }

    // SWAPPED operands: D' = D^T. acc[mi][ni]: col(lane&15) = speaker
    // (row0 + wr*128 + mi*16 + l15), row((lane>>4)*4+r) = test
    // (col0 + wc*64 + ni*16 + (lane>>4)*4 + r).
#define MM(BF, MIH, NIH)                                                       \
    {                                                                          \
        __builtin_amdgcn_s_setprio(1);                                         \
        _Pragma("unroll") for (int j_ = 0; j_ < 4; ++j_)                       \
            _Pragma("unroll") for (int n_ = 0; n_ < 2; ++n_)                   \
                _Pragma("unroll") for (int k_ = 0; k_ < 2; ++k_)               \
                    acc[(MIH) * 4 + j_][(NIH) * 2 + n_] =                      \
                        __builtin_amdgcn_mfma_f32_16x16x32_bf16(               \
                            BF[n_ * 2 + k_], af[j_ * 2 + k_],                  \
                            acc[(MIH) * 4 + j_][(NIH) * 2 + n_], 0, 0, 0);     \
        __builtin_amdgcn_s_setprio(0);                                         \
    }

#define VM4 asm volatile("s_waitcnt vmcnt(4)" ::: "memory")
#define VM0 asm volatile("s_waitcnt vmcnt(0)" ::: "memory")
#define BAR __builtin_amdgcn_s_barrier()

    f32x4 acc[8][4] = {};
    short8 af[8], bf0[4], bf1[4];

    // ---- prologue: T0 full (4 halves) + T1-B (2 halves); confirm T0.
    STAGE_H(0, 0, 0, 0) STAGE_H(0, 0, 1, 0) STAGE_H(1, 0, 0, 0) STAGE_H(1, 0, 1, 0)
    STAGE_H(1, 1, 0, 1) STAGE_H(1, 1, 1, 1)
    if (tid < 256) { rowsum[tid] = 0.f; possum[tid] = 0.f; }
    VM4;                       // T0's 8 loads landed; T1-B (4) in flight
    BAR;

    // ---- main loop: 4 iterations x 8 phases, 2 K-tiles each.
#pragma unroll
    for (int it = 0; it < 4; ++it) {
        LDA8(0, 0) LDB4(bf0, 0, 0)
        STAGE_H(0, 1, 0, 2 * it + 1)
        BAR; MM(bf0, 0, 0) BAR;

        LDB4(bf1, 0, 1)
        STAGE_H(0, 1, 1, 2 * it + 1)
        BAR; MM(bf1, 0, 1) BAR;

        LDA8(0, 1)
        if (it < 3) STAGE_H(1, 0, 0, 2 * it + 2)
        BAR; MM(bf1, 1, 1) BAR;

        if (it < 3) { STAGE_H(1, 0, 1, 2 * it + 2) VM4; } else { VM0; }
        BAR; MM(bf0, 1, 0) BAR;

        LDA8(1, 0) LDB4(bf0, 1, 0)
        if (it < 3) STAGE_H(0, 0, 0, 2 * it + 2)
        BAR; MM(bf0, 0, 0) BAR;

        LDB4(bf1, 1, 1)
        if (it < 3) STAGE_H(0, 0, 1, 2 * it + 2)
        BAR; MM(bf1, 0, 1) BAR;

        LDA8(1, 1)
        if (it < 3) STAGE_H(1, 1, 0, 2 * it + 3)
        BAR; MM(bf1, 1, 1) BAR;

        if (it < 3) { STAGE_H(1, 1, 1, 2 * it + 3) VM4; }
        BAR; MM(bf0, 1, 0) BAR;
    }
#undef STAGE_H
#undef LDA8
#undef LDB4
#undef MM
#undef VM4
#undef VM0
#undef BAR

    // ---- epilogue (swapped layout): per-speaker sum = 16 VALU adds over
    // (ni,r) + 2 shuffles over lane>>4; speaker = lane&15 within mi-group.
    const int bcol = col0 + wc * 64;
    const int k4 = (lane >> 4) << 2;
#pragma unroll
    for (int mi = 0; mi < 8; ++mi) {
        const int lspk = wr * 128 + mi * 16 + l15;     // local speaker row
        const int gs = row0 + lspk;                    // global speaker
        float t = 0.f, p = 0.f;
#pragma unroll
        for (int ni = 0; ni < 4; ++ni) {
#pragma unroll
            for (int r = 0; r < 4; ++r) {
                const float e = __expf(fmaf(alpha, acc[mi][ni][r], beta));
                t += e;
                if (has_diag) {
                    const int gt = bcol + ni * 16 + k4 + r;   // global test row
                    p += ((gt >> 4) == gs) ? e : 0.f;
                }
            }
        }
        t += __shfl_xor(t, 16, 64);
        t += __shfl_xor(t, 32, 64);
        if (lane < 16) atomicAdd(&rowsum[lspk], t);
        if (has_diag) {
            p += __shfl_xor(p, 16, 64);
            p += __shfl_xor(p, 32, 64);
            if (lane < 16) atomicAdd(&possum[lspk], p);
        }
    }
    __syncthreads();
    if (tid < 256) {
        atomicAdd(&g_row[row0 + tid], rowsum[tid]);
        if (has_diag) atomicAdd(&g_pos[row0 + tid], possum[tid]);
    }
}

// ---------------------------------------------------------------------------
// Kernel 3: loss = mean(log(tot - pos) - log(pos)) — shfl-based, 1 barrier.
// ---------------------------------------------------------------------------
__global__ __launch_bounds__(1024) void finalize_kernel(const float* __restrict__ g_row,
                                                        const float* __restrict__ g_pos,
                                                        float* __restrict__ out) {
    __shared__ float wsum[16];
    const int i = threadIdx.x;
    const int lane = i & 63, wid = i >> 6;
    const float pos = g_pos[i];
    const float neg = g_row[i] - pos;
    float v = logf(fmaxf(neg, 1e-30f)) - logf(fmaxf(pos, 1e-30f));
#pragma unroll
    for (int m = 1; m < 64; m <<= 1) v += __shfl_xor(v, m, 64);
    if (lane == 0) wsum[wid] = v;
    __syncthreads();
    if (i < 64) {
        float s = (i < 16) ? wsum[i] : 0.f;
#pragma unroll
        for (int m = 1; m < 16; m <<= 1) s += __shfl_xor(s, m, 64);
        if (i == 0) out[0] = s * (1.f / 1024.f);
    }
}

extern "C" void kernel_launch(void* const* d_in, const int* in_sizes, int n_in,
                              void* d_out, int out_size, void* d_ws, size_t ws_size,
                              hipStream_t stream) {
    const float* emb = (const float*)d_in[0];
    // d_in[1] = labels (unused; structure fixed by construction)
    const float* alpha_p = (const float*)d_in[2];
    const float* beta_p = (const float*)d_in[3];

    unsigned short* cent = (unsigned short*)d_ws;          // 1024*512 bf16 = 1 MB
    unsigned short* test = cent + (size_t)N_SPK * D;       // 16384*512 bf16 = 16 MB
    float* g_row = (float*)(test + (size_t)N_TEST_ROWS * D);
    float* g_pos = g_row + N_SPK;

    prep_kernel<<<N_SPK + N_TEST_ROWS / 4, 256, 0, stream>>>(emb, cent, test, g_row, g_pos);

    gemm_kernel<<<256, 512, 0, stream>>>(cent, test, alpha_p, beta_p, g_row, g_pos);

    finalize_kernel<<<1, 1024, 0, stream>>>(g_row, g_pos, (float*)d_out);
}